// Round 1
// baseline (392.122 us; speedup 1.0000x reference)
//
#include <hip/hip_runtime.h>
#include <math.h>

#define N_NODES 20000
#define N_EDGES 160000
#define AGG_STRIDE 644   // 640 + 4 pad (keeps 16B align, breaks bank aliasing)
#define Y_STRIDE 68

#define PI_F 3.14159265358979323846f
#define LN2_F 0.69314718055994530942f

__device__ __forceinline__ float sspf(float x) {
    // softplus(x) - ln2, numerically stable
    return fmaxf(x, 0.0f) + log1pf(expf(-fabsf(x))) - LN2_F;
}

__device__ __forceinline__ void fma4(float4& a, float s, const float4& w) {
    a.x = fmaf(s, w.x, a.x);
    a.y = fmaf(s, w.y, a.y);
    a.z = fmaf(s, w.z, a.z);
    a.w = fmaf(s, w.w, a.w);
}

// ---------------------------------------------------------------------------
// Precompute w[e, n, b] = switch[e] * rb[e, n] * bond_order[e, b]   (E x 40)
// rb[n] = sqrt(2/5) * sin((n+1) * pi * r / 5) / r
// ---------------------------------------------------------------------------
__global__ __launch_bounds__(256) void edge_w_kernel(
    const float* __restrict__ dist,
    const float* __restrict__ sw,
    const float* __restrict__ bo,
    float* __restrict__ w)
{
    int e = blockIdx.x * blockDim.x + threadIdx.x;
    if (e >= N_EDGES) return;
    float r = dist[e];
    float c = sqrtf(2.0f / 5.0f) / r * sw[e];
    float bov[5];
    #pragma unroll
    for (int b = 0; b < 5; ++b) bov[b] = bo[e * 5 + b];
    float out[40];
    #pragma unroll
    for (int n = 0; n < 8; ++n) {
        float rbn = c * sinf((float)(n + 1) * PI_F * r * 0.2f);
        #pragma unroll
        for (int b = 0; b < 5; ++b) out[n * 5 + b] = rbn * bov[b];
    }
    float4* wp4 = reinterpret_cast<float4*>(w + (size_t)e * 40);
    #pragma unroll
    for (int i = 0; i < 10; ++i)
        wp4[i] = make_float4(out[4 * i], out[4 * i + 1], out[4 * i + 2], out[4 * i + 3]);
}

// ---------------------------------------------------------------------------
// CSR offsets from sorted edge_src: row[i] = lower_bound(edge_src, i)
// ---------------------------------------------------------------------------
__global__ __launch_bounds__(256) void row_start_kernel(
    const int* __restrict__ src, int* __restrict__ row)
{
    int i = blockIdx.x * blockDim.x + threadIdx.x;
    if (i > N_NODES) return;
    int lo = 0, hi = N_EDGES;
    while (lo < hi) {
        int mid = (lo + hi) >> 1;
        if (src[mid] < i) lo = mid + 1; else hi = mid;
    }
    row[i] = lo;
}

// ---------------------------------------------------------------------------
// xi = W_species[species]   (N x 64, written into d_out)
// ---------------------------------------------------------------------------
__global__ __launch_bounds__(256) void xi_init_kernel(
    const int* __restrict__ species,
    const float* __restrict__ Wsp,
    float* __restrict__ xi)
{
    int idx = blockIdx.x * blockDim.x + threadIdx.x; // float4 index
    if (idx >= N_NODES * 16) return;
    int node = idx >> 4;
    int c4 = idx & 15;
    int sp = species[node];
    reinterpret_cast<float4*>(xi)[idx] =
        reinterpret_cast<const float4*>(Wsp + (size_t)sp * 64)[c4];
}

// ---------------------------------------------------------------------------
// h = xi @ Wl[l] + bl[l]   (N x 32); si = h[:, :16], mi = h[:, 16:]
// 32 nodes per block of 256
// ---------------------------------------------------------------------------
__global__ __launch_bounds__(256) void h_kernel(
    const float* __restrict__ xi,
    const float* __restrict__ Wl,   // 64 x 32 (layer slice)
    const float* __restrict__ bl,   // 32
    float* __restrict__ h)
{
    __shared__ float xs[32 * 64];
    __shared__ float ws[64 * 32];
    int tid = threadIdx.x;
    int nb = blockIdx.x * 32;

    const float4* xsrc = reinterpret_cast<const float4*>(xi + (size_t)nb * 64);
    float4* xd = reinterpret_cast<float4*>(xs);
    #pragma unroll
    for (int i = 0; i < 2; ++i) xd[tid + i * 256] = xsrc[tid + i * 256];
    const float4* wsrc = reinterpret_cast<const float4*>(Wl);
    float4* wd = reinterpret_cast<float4*>(ws);
    #pragma unroll
    for (int i = 0; i < 2; ++i) wd[tid + i * 256] = wsrc[tid + i * 256];
    __syncthreads();

    int c = tid & 31;
    int ng = tid >> 5; // 0..7
    float bias = bl[c];
    float acc[4] = {bias, bias, bias, bias};
    for (int j = 0; j < 64; ++j) {
        float wv = ws[j * 32 + c];
        #pragma unroll
        for (int q = 0; q < 4; ++q)
            acc[q] = fmaf(xs[(ng * 4 + q) * 64 + j], wv, acc[q]);
    }
    #pragma unroll
    for (int q = 0; q < 4; ++q)
        h[(size_t)(nb + ng * 4 + q) * 32 + c] = acc[q];
}

// ---------------------------------------------------------------------------
// Fused per-layer kernel: edge aggregation (into LDS) + FC1/ssp + FC2/ssp +
// FC3 + xi residual update.  16 nodes per block of 256 (4 waves).
// Output layout o = n*80 + s*5 + b; lane L owns outputs [10L, 10L+10):
//   n = L/8 (const per lane), s0 = (L%8)*2, b = j%5, s = s0 + j/5
// ---------------------------------------------------------------------------
__global__ __launch_bounds__(256) void agg_fc_kernel(
    const float* __restrict__ w,     // E x 40
    const int* __restrict__ row,     // N+1
    const int* __restrict__ dst,     // E
    const float* __restrict__ h,     // N x 32
    const float* __restrict__ W1, const float* __restrict__ b1,
    const float* __restrict__ W2, const float* __restrict__ b2,
    const float* __restrict__ W3, const float* __restrict__ b3,
    float* __restrict__ xi)          // N x 64 (in/out)
{
    __shared__ float agg[16 * AGG_STRIDE];  // 41216 B
    __shared__ float wlds[64 * 64];         // 16384 B
    __shared__ float ylds[16 * Y_STRIDE];   //  4352 B

    int tid = threadIdx.x;
    int nb0 = blockIdx.x * 16;
    int lane = tid & 63;
    int g = tid >> 6;

    // ---- aggregation: wave g handles nodes t = 4g .. 4g+3 ----
    int n_idx = lane >> 3;
    int s0 = (lane & 7) * 2;
    for (int m = 0; m < 4; ++m) {
        int t = g * 4 + m;
        int node = nb0 + t;
        int e0 = row[node], e1 = row[node + 1];
        float acc[10];
        #pragma unroll
        for (int j = 0; j < 10; ++j) acc[j] = 0.0f;
        for (int e = e0; e < e1; ++e) {
            int d = dst[e];
            const float* wp = w + (size_t)e * 40 + n_idx * 5;
            float w0 = wp[0], w1 = wp[1], w2 = wp[2], w3 = wp[3], w4 = wp[4];
            const float* mp = h + (size_t)d * 32 + 16 + s0;
            float v0 = mp[0], v1 = mp[1];
            acc[0] = fmaf(w0, v0, acc[0]);
            acc[1] = fmaf(w1, v0, acc[1]);
            acc[2] = fmaf(w2, v0, acc[2]);
            acc[3] = fmaf(w3, v0, acc[3]);
            acc[4] = fmaf(w4, v0, acc[4]);
            acc[5] = fmaf(w0, v1, acc[5]);
            acc[6] = fmaf(w1, v1, acc[6]);
            acc[7] = fmaf(w2, v1, acc[7]);
            acc[8] = fmaf(w3, v1, acc[8]);
            acc[9] = fmaf(w4, v1, acc[9]);
        }
        float* ap = agg + t * AGG_STRIDE + lane * 10;
        #pragma unroll
        for (int j = 0; j < 10; ++j) ap[j] = acc[j];
    }
    __syncthreads();

    // ---- FC phase: thread owns node t = tid>>4, cols k = 4*(tid&15)..+3 ----
    int t = tid >> 4;
    int kg = tid & 15;
    int node = nb0 + t;

    float4 acc1 = *reinterpret_cast<const float4*>(b1 + kg * 4);

    // 10 chunks of 64 rows over the 640 aggregated features
    for (int c = 0; c < 10; ++c) {
        const float4* wsrc = reinterpret_cast<const float4*>(W1 + (size_t)c * 64 * 64);
        float4* wd = reinterpret_cast<float4*>(wlds);
        #pragma unroll
        for (int i = 0; i < 4; ++i) wd[tid + i * 256] = wsrc[tid + i * 256];
        __syncthreads();

        const float* ar = agg + t * AGG_STRIDE + c * 64;
        #pragma unroll
        for (int jj = 0; jj < 64; jj += 4) {
            float4 xv = *reinterpret_cast<const float4*>(ar + jj);
            const float* wb = wlds + jj * 64 + kg * 4;
            fma4(acc1, xv.x, *reinterpret_cast<const float4*>(wb));
            fma4(acc1, xv.y, *reinterpret_cast<const float4*>(wb + 64));
            fma4(acc1, xv.z, *reinterpret_cast<const float4*>(wb + 128));
            fma4(acc1, xv.w, *reinterpret_cast<const float4*>(wb + 192));
        }
        __syncthreads();
    }
    // si chunk: W1 rows 640..655, x = h[node, 0:16]
    {
        const float4* wsrc = reinterpret_cast<const float4*>(W1 + (size_t)640 * 64);
        float4* wd = reinterpret_cast<float4*>(wlds);
        wd[tid] = wsrc[tid]; // 16*64 floats = 256 float4
        __syncthreads();
        const float* sp = h + (size_t)node * 32;
        #pragma unroll
        for (int j = 0; j < 16; ++j) {
            float xv = sp[j];
            fma4(acc1, xv, *reinterpret_cast<const float4*>(wlds + j * 64 + kg * 4));
        }
    }
    // ssp + write y1
    {
        float* yp = ylds + t * Y_STRIDE + kg * 4;
        yp[0] = sspf(acc1.x);
        yp[1] = sspf(acc1.y);
        yp[2] = sspf(acc1.z);
        yp[3] = sspf(acc1.w);
    }
    __syncthreads(); // all reads of W1-si chunk done; y1 visible

    // ---- FC2 ----
    {
        const float4* wsrc = reinterpret_cast<const float4*>(W2);
        float4* wd = reinterpret_cast<float4*>(wlds);
        #pragma unroll
        for (int i = 0; i < 4; ++i) wd[tid + i * 256] = wsrc[tid + i * 256];
    }
    __syncthreads();
    float4 acc2 = *reinterpret_cast<const float4*>(b2 + kg * 4);
    {
        const float* yr = ylds + t * Y_STRIDE;
        #pragma unroll
        for (int jj = 0; jj < 64; jj += 4) {
            float4 xv = *reinterpret_cast<const float4*>(yr + jj);
            const float* wb = wlds + jj * 64 + kg * 4;
            fma4(acc2, xv.x, *reinterpret_cast<const float4*>(wb));
            fma4(acc2, xv.y, *reinterpret_cast<const float4*>(wb + 64));
            fma4(acc2, xv.z, *reinterpret_cast<const float4*>(wb + 128));
            fma4(acc2, xv.w, *reinterpret_cast<const float4*>(wb + 192));
        }
        // write y2 over y1 (same-wave rows, lockstep-safe)
        float* yp = ylds + t * Y_STRIDE + kg * 4;
        yp[0] = sspf(acc2.x);
        yp[1] = sspf(acc2.y);
        yp[2] = sspf(acc2.z);
        yp[3] = sspf(acc2.w);
    }
    __syncthreads(); // all W2 reads done before W3 overwrite

    // ---- FC3 + residual ----
    {
        const float4* wsrc = reinterpret_cast<const float4*>(W3);
        float4* wd = reinterpret_cast<float4*>(wlds);
        #pragma unroll
        for (int i = 0; i < 4; ++i) wd[tid + i * 256] = wsrc[tid + i * 256];
    }
    __syncthreads();
    float4 acc3 = *reinterpret_cast<const float4*>(b3 + kg * 4);
    {
        const float* yr = ylds + t * Y_STRIDE;
        #pragma unroll
        for (int jj = 0; jj < 64; jj += 4) {
            float4 xv = *reinterpret_cast<const float4*>(yr + jj);
            const float* wb = wlds + jj * 64 + kg * 4;
            fma4(acc3, xv.x, *reinterpret_cast<const float4*>(wb));
            fma4(acc3, xv.y, *reinterpret_cast<const float4*>(wb + 64));
            fma4(acc3, xv.z, *reinterpret_cast<const float4*>(wb + 128));
            fma4(acc3, xv.w, *reinterpret_cast<const float4*>(wb + 192));
        }
    }
    float* xp = xi + (size_t)node * 64 + kg * 4;
    float4 old = *reinterpret_cast<const float4*>(xp);
    old.x += acc3.x; old.y += acc3.y; old.z += acc3.z; old.w += acc3.w;
    *reinterpret_cast<float4*>(xp) = old;
}

// ---------------------------------------------------------------------------
extern "C" void kernel_launch(void* const* d_in, const int* in_sizes, int n_in,
                              void* d_out, int out_size, void* d_ws, size_t ws_size,
                              hipStream_t stream) {
    const int*   species = (const int*)d_in[0];
    const int*   esrc    = (const int*)d_in[1];
    const int*   edst    = (const int*)d_in[2];
    const float* dist    = (const float*)d_in[3];
    const float* sw      = (const float*)d_in[4];
    const float* bo      = (const float*)d_in[5];
    const float* Wsp     = (const float*)d_in[6];
    const float* Wl      = (const float*)d_in[7];
    const float* bl      = (const float*)d_in[8];
    const float* fcW1    = (const float*)d_in[9];
    const float* fcb1    = (const float*)d_in[10];
    const float* fcW2    = (const float*)d_in[11];
    const float* fcb2    = (const float*)d_in[12];
    const float* fcW3    = (const float*)d_in[13];
    const float* fcb3    = (const float*)d_in[14];
    float* xi = (float*)d_out;

    char* ws = (char*)d_ws;
    float* w_edge = (float*)ws;                   // 25,600,000 B
    int*   rowp   = (int*)(ws + 25600000);        //     80,128 B (padded)
    float* h      = (float*)(ws + 25680128);      //  2,560,000 B

    hipLaunchKernelGGL(edge_w_kernel, dim3(625), dim3(256), 0, stream,
                       dist, sw, bo, w_edge);
    hipLaunchKernelGGL(row_start_kernel, dim3(79), dim3(256), 0, stream,
                       esrc, rowp);
    hipLaunchKernelGGL(xi_init_kernel, dim3(1250), dim3(256), 0, stream,
                       species, Wsp, xi);

    for (int l = 0; l < 3; ++l) {
        hipLaunchKernelGGL(h_kernel, dim3(625), dim3(256), 0, stream,
                           xi, Wl + (size_t)l * 64 * 32, bl + (size_t)l * 32, h);
        hipLaunchKernelGGL(agg_fc_kernel, dim3(1250), dim3(256), 0, stream,
                           w_edge, rowp, edst, h,
                           fcW1 + (size_t)l * 656 * 64, fcb1 + (size_t)l * 64,
                           fcW2 + (size_t)l * 64 * 64,  fcb2 + (size_t)l * 64,
                           fcW3 + (size_t)l * 64 * 64,  fcb3 + (size_t)l * 64,
                           xi);
    }
}